// Round 1
// 534.119 us; speedup vs baseline: 1.0341x; 1.0341x over previous
//
#include <hip/hip_runtime.h>
#include <stdint.h>

#define BATCH 16
#define CDIM 64
#define NDIM 65536
#define EPSV 1e-6f

typedef __attribute__((ext_vector_type(8))) _Float16 f16x8;
typedef __attribute__((ext_vector_type(4))) float f32x4;
typedef __attribute__((ext_vector_type(4))) uint32_t u32x4;
typedef __attribute__((ext_vector_type(4))) short s16x4;

static __device__ __forceinline__ short h2s(_Float16 h) {
    return (short)__builtin_bit_cast(unsigned short, h);
}
static __device__ __forceinline__ _Float16 s2h(short s) {
    return __builtin_bit_cast(_Float16, (unsigned short)s);
}

// ---------------- Kernel 1: Gram partials + tvec partials + persist u ----------------
// grid 1024 = 16 batches x 64 tiles; each block: 4 chunks of 256 positions.
// NEW: writes u = fp16(v * sqrt(inv_norm)) position-major [n][64c] (128 MB, L3-half)
// plus per-position meta {colsum, sqrt(inv)} so out_kernel never re-reads x.
#define T1 256
#define P1 264   // fp16 row pitch; 528 B rows, 16B-aligned b128 frags
#define CHUNKS 4
#define NTILE1 64

__global__ __launch_bounds__(256, 4)
void gram_kernel(const float* __restrict__ x, float* __restrict__ pmat,
                 float* __restrict__ pt, short* __restrict__ ut,
                 float2* __restrict__ meta) {
    __shared__ __align__(16) short ldsU[CDIM][P1];
    __shared__ __align__(16) float ldsG[T1];
    __shared__ float red[4][CDIM];

    const int tid = threadIdx.x;
    const int b = blockIdx.x >> 6;
    const int tileIdx = blockIdx.x & 63;
    const int w = tid >> 6;
    const int lane = tid & 63;
    const int cq = lane >> 4;
    const int cr = lane & 15;

    f32x4 acc0 = {0.f, 0.f, 0.f, 0.f};
    f32x4 acc1 = acc0, acc2 = acc0, acc3 = acc0;
    float tpart = 0.f;

    const float* xbase = x + (size_t)b * CDIM * NDIM;

    for (int chunk = 0; chunk < CHUNKS; ++chunk) {
        const int n0 = tileIdx * (T1 * CHUNKS) + chunk * T1;
        const int n = n0 + tid;                 // thread owns one position
        const float* xb = xbase + n;
        float ss = 0.f, cs = 0.f;
#pragma unroll 8
        for (int c = 0; c < CDIM; ++c) {
            float v = __builtin_nontemporal_load(xb + (size_t)c * NDIM);
            ss += v * v;
            cs += v;
            ldsU[c][tid] = h2s((_Float16)v);    // fp16: 1-op hw convert
        }
        const float inv = 1.f / (sqrtf(ss) + EPSV);
        const float sq = sqrtf(inv);
        const _Float16 sqh = (_Float16)sq;
        ldsG[tid] = inv * sq * cs;              // g = inv^1.5 * colsum
        // store meta with the ROUNDED scale so out_kernel's rcp cancels exactly
        meta[(size_t)b * NDIM + n] = make_float2(cs, (float)sqh);
        // rescale own column in place AND persist u row (position-major) to global
        short* urow = ut + ((size_t)b * NDIM + n) * CDIM;
#pragma unroll
        for (int c8 = 0; c8 < CDIM; c8 += 8) {
            uint32_t pk0, pk1, pk2, pk3;
#pragma unroll
            for (int j = 0; j < 4; ++j) {
                _Float16 u0 = s2h(ldsU[c8 + 2 * j][tid]) * sqh;
                _Float16 u1 = s2h(ldsU[c8 + 2 * j + 1][tid]) * sqh;
                ldsU[c8 + 2 * j][tid] = h2s(u0);
                ldsU[c8 + 2 * j + 1][tid] = h2s(u1);
                uint32_t p = (uint32_t)__builtin_bit_cast(unsigned short, u0) |
                             ((uint32_t)__builtin_bit_cast(unsigned short, u1) << 16);
                if (j == 0) pk0 = p; else if (j == 1) pk1 = p;
                else if (j == 2) pk2 = p; else pk3 = p;
            }
            *(u32x4*)(urow + c8) = (u32x4){pk0, pk1, pk2, pk3};
        }
        __syncthreads();
        // MFMA Gram (fp16): wave w -> rows [16w,16w+16) x all 64 cols, K=256
#pragma unroll
        for (int ks = 0; ks < 8; ++ks) {
            const int k0 = ks * 32 + cq * 8;
            f16x8 afrag = *(const f16x8*)&ldsU[w * 16 + cr][k0];
            f16x8 b0 = *(const f16x8*)&ldsU[cr][k0];
            f16x8 b1 = *(const f16x8*)&ldsU[16 + cr][k0];
            f16x8 b2 = *(const f16x8*)&ldsU[32 + cr][k0];
            f16x8 b3 = *(const f16x8*)&ldsU[48 + cr][k0];
            acc0 = __builtin_amdgcn_mfma_f32_16x16x32_f16(afrag, b0, acc0, 0, 0, 0);
            acc1 = __builtin_amdgcn_mfma_f32_16x16x32_f16(afrag, b1, acc1, 0, 0, 0);
            acc2 = __builtin_amdgcn_mfma_f32_16x16x32_f16(afrag, b2, acc2, 0, 0, 0);
            acc3 = __builtin_amdgcn_mfma_f32_16x16x32_f16(afrag, b3, acc3, 0, 0, 0);
        }
        // tvec partial: row = lane (channel), wave slice = 64 positions
#pragma unroll
        for (int i = 0; i < 8; ++i) {
            const int nb = w * 64 + i * 8;
            f16x8 uf = *(const f16x8*)&ldsU[lane][nb];
            f32x4 g0 = *(const f32x4*)&ldsG[nb];
            f32x4 g1 = *(const f32x4*)&ldsG[nb + 4];
#pragma unroll
            for (int j = 0; j < 4; ++j) {
                tpart += (float)uf[j] * g0[j];
                tpart += (float)uf[j + 4] * g1[j];
            }
        }
        __syncthreads();
    }
    // reduce tvec partial across waves, emit per-block partials (no atomics)
    red[w][lane] = tpart;
    __syncthreads();
    if (tid < CDIM) {
        pt[(size_t)blockIdx.x * CDIM + tid] =
            red[0][tid] + red[1][tid] + red[2][tid] + red[3][tid];
    }
    // emit Gram partial: C/D layout col=lane&15, row=quad*4+reg
    float* pm = pmat + (size_t)blockIdx.x * CDIM * CDIM;
    const f32x4 accs[4] = {acc0, acc1, acc2, acc3};
#pragma unroll
    for (int mt = 0; mt < 4; ++mt) {
#pragma unroll
        for (int r = 0; r < 4; ++r) {
            const int row = w * 16 + cq * 4 + r;
            const int col = mt * 16 + cr;
            pm[row * CDIM + col] = accs[mt][r];
        }
    }
}

// ---------------- Kernel 1.5: reduce partials -> matb (fp16), tailor ----------------
__global__ __launch_bounds__(256, 4)
void reduce_kernel(const float* __restrict__ pmat, const float* __restrict__ pt,
                   short* __restrict__ matb, float* __restrict__ tl) {
    const int blk = blockIdx.x;
    const int tid = threadIdx.x;
    if (blk < 256) {            // mat: 16 batches x 4096 elems
        const int b = blk >> 4;
        const int o = (blk & 15) * 256 + tid;
        float s = 0.f;
#pragma unroll 8
        for (int t = 0; t < NTILE1; ++t)
            s += __builtin_nontemporal_load(
                &pmat[((size_t)(b * NTILE1 + t)) * (CDIM * CDIM) + o]);
        matb[(size_t)b * CDIM * CDIM + o] = h2s((_Float16)s);
    } else {                    // tailor: 16 x 64
        const int idx = (blk - 256) * 256 + tid;
        const int b = idx >> 6;
        const int c = idx & 63;
        float s = 0.f;
#pragma unroll 8
        for (int t = 0; t < NTILE1; ++t)
            s += __builtin_nontemporal_load(&pt[(size_t)(b * NTILE1 + t) * CDIM + c]);
        tl[idx] = 1.f / ((float)NDIM + s + EPSV);
    }
}

// ---------------- Kernel 2: matvec + fused epilogue, no x re-read ----------------
// B-fragments come straight from global u (position-major row == fragment line).
// LDS only holds the 8 KB fp16 matrix -> high occupancy, no ldsV, no barriers in
// the main loop. Reversed block order so u reads chase kernel 1's L3 tail.
#define PM 72    // matrix fp16 pitch: 144 B rows, 16B-aligned b128 frags

__global__ __launch_bounds__(256, 3)
void out_kernel(const short* __restrict__ ut, const short* __restrict__ matb,
                const float* __restrict__ tl, const float2* __restrict__ meta,
                const float* __restrict__ gamma, float* __restrict__ out) {
    __shared__ __align__(16) short ldsM[CDIM][PM];
    __shared__ float ldsTL[CDIM];

    const int tid = threadIdx.x;
    const int bid = (int)(gridDim.x - 1 - blockIdx.x);
    const int b = bid >> 8;
    const int n0 = (bid & 255) * 256;
    const int w = tid >> 6;
    const int lane = tid & 63;
    const int cq = lane >> 4;
    const int cr = lane & 15;

    // stage matrix (fp16, 8 KB) + tailor
    {
        const short* mb = matb + (size_t)b * CDIM * CDIM;
        const int c = tid >> 2;
        const int seg = (tid & 3) * 16;
        u32x4 q0 = *(const u32x4*)(mb + c * CDIM + seg);
        u32x4 q1 = *(const u32x4*)(mb + c * CDIM + seg + 8);
        *(u32x4*)&ldsM[c][seg] = q0;
        *(u32x4*)&ldsM[c][seg + 8] = q1;
    }
    if (tid < CDIM) ldsTL[tid] = tl[b * CDIM + tid];
    __syncthreads();

    // A-frags from matrix: A[c][k=m]
    f16x8 afrag[4][2];
#pragma unroll
    for (int ct = 0; ct < 4; ++ct)
#pragma unroll
        for (int ks = 0; ks < 2; ++ks)
            afrag[ct][ks] = *(const f16x8*)&ldsM[ct * 16 + cr][ks * 32 + cq * 8];

    f32x4 acc[4][4];
#pragma unroll
    for (int p = 0; p < 4; ++p)
#pragma unroll
        for (int ct = 0; ct < 4; ++ct)
            acc[p][ct] = (f32x4){0.f, 0.f, 0.f, 0.f};

    const short* ub = ut + (size_t)b * NDIM * CDIM;

    // D(64 x 256) = M(64x64) @ U^T; wave w handles pos-tiles 4w..4w+3
#pragma unroll
    for (int p = 0; p < 4; ++p) {
        const int n = n0 + (w * 4 + p) * 16 + cr;
        const short* urow = ub + (size_t)n * CDIM;
#pragma unroll
        for (int ks = 0; ks < 2; ++ks) {
            f16x8 bfrag = *(const f16x8*)(urow + ks * 32 + cq * 8);
#pragma unroll
            for (int ct = 0; ct < 4; ++ct)
                acc[p][ct] = __builtin_amdgcn_mfma_f32_16x16x32_f16(
                    afrag[ct][ks], bfrag, acc[p][ct], 0, 0, 0);
        }
    }

    // epilogue: out = u*rs + gamma * tl[c] * (cs[n] + s[n]*y[c,n]); rs = 1/s
    const float g = gamma[0];
    float* obase = out + (size_t)b * CDIM * NDIM;
#pragma unroll
    for (int p = 0; p < 4; ++p) {
        const int n = n0 + (w * 4 + p) * 16 + cr;
        const float2 ms = meta[(size_t)b * NDIM + n];
        const float csn = ms.x;
        const float sn = ms.y;
        const float rs = 1.0f / sn;             // cancels stored fp16 scale exactly
        const short* urow = ub + (size_t)n * CDIM;
#pragma unroll
        for (int ct = 0; ct < 4; ++ct) {
            const int c0 = ct * 16 + cq * 4;
            s16x4 uv = *(const s16x4*)(urow + c0);
#pragma unroll
            for (int r = 0; r < 4; ++r) {
                const int c = c0 + r;
                float val = (float)s2h(uv[r]) * rs +
                            g * ldsTL[c] * (csn + sn * acc[p][ct][r]);
                __builtin_nontemporal_store(val, obase + (size_t)c * NDIM + n);
            }
        }
    }
}

extern "C" void kernel_launch(void* const* d_in, const int* in_sizes, int n_in,
                              void* d_out, int out_size, void* d_ws, size_t ws_size,
                              hipStream_t stream) {
    const float* x = (const float*)d_in[0];
    const float* gamma = (const float*)d_in[1];
    float* out = (float*)d_out;
    // workspace layout (f32 slots):
    float* ws = (float*)d_ws;
    short* ut = (short*)ws;                                   // 16*65536*64 fp16 = 128 MB
    float* pmat = ws + (size_t)33554432;                      // 1024 x 4096 f32
    float* pt = pmat + (size_t)1024 * CDIM * CDIM;            // 1024 x 64 f32
    float2* meta = (float2*)(pt + (size_t)1024 * CDIM);       // 16 x 65536 float2
    short* matb = (short*)((float*)meta + (size_t)2 * BATCH * NDIM); // 16 x 4096 fp16
    float* tl = (float*)(matb + (size_t)BATCH * CDIM * CDIM); // 16 x 64 f32

    hipLaunchKernelGGL(gram_kernel, dim3(BATCH * NTILE1), dim3(256), 0, stream,
                       x, pmat, pt, ut, meta);
    hipLaunchKernelGGL(reduce_kernel, dim3(260), dim3(256), 0, stream,
                       pmat, pt, matb, tl);
    hipLaunchKernelGGL(out_kernel, dim3(BATCH * 256), dim3(256), 0, stream,
                       ut, matb, tl, meta, gamma, out);
}